// Round 1
// baseline (3432.760 us; speedup 1.0000x reference)
//
#include <hip/hip_runtime.h>

#define BB 64
#define PP 33
#define IMG 1089        // 33*33
#define MM 272
#define NP1 9
#define NPATCH 81
#define KK 7
#define KK2 49
#define CATT 16
#define PADW 39
#define PIMG 1521       // 39*39
#define SC_NP 27
#define AG_NP 27

static __host__ __device__ inline int cdiv_i(int a, int b) { return (a + b - 1) / b; }

// ---------------- Phi forward: Phi_x[b,m] = <x[b], PhiW[m]>, aubru = mu*(Phi_x - Phix) - ru
__global__ __launch_bounds__(256) void k_phi(
    const float* __restrict__ x, const float* __restrict__ PhiW,
    const float* __restrict__ Phix_in, const float* __restrict__ ru,
    const float* __restrict__ mu_p,
    float* __restrict__ Phi_x, float* __restrict__ aubru)
{
    int b = blockIdx.x, tid = threadIdx.x;
    __shared__ float xs[IMG];
    for (int i = tid; i < IMG; i += 256) xs[i] = x[b * IMG + i];
    __syncthreads();
    float mu = mu_p[0];
    for (int m = tid; m < MM; m += 256) {
        const float* w = PhiW + (size_t)m * IMG;
        float acc = 0.f;
        #pragma unroll 4
        for (int j = 0; j < IMG; ++j) acc += xs[j] * w[j];
        Phi_x[b * MM + m] = acc;
        aubru[b * MM + m] = mu * (acc - Phix_in[b * MM + m]) - ru[b * MM + m];
    }
}

// ---------------- du = relu(conv3x3_1ch(x)), duv = du - v/beta + ls2*(PhiTb - PhiT(Phi_x)), wa = PhiT(aubru)
__global__ __launch_bounds__(256) void k_duv(
    const float* __restrict__ x, const float* __restrict__ v_in,
    const float* __restrict__ PhiTb, const float* __restrict__ PhiTW,
    const float* __restrict__ Phi_x, const float* __restrict__ aubru,
    const float* __restrict__ conv1_w,
    const float* __restrict__ beta_p, const float* __restrict__ ls2_p,
    float* __restrict__ du, float* __restrict__ duv, float* __restrict__ wa)
{
    int b = blockIdx.x, tid = threadIdx.x;
    __shared__ float xs[IMG];
    __shared__ float ps[MM], as_[MM];
    for (int i = tid; i < IMG; i += 256) xs[i] = x[b * IMG + i];
    for (int i = tid; i < MM; i += 256) { ps[i] = Phi_x[b * MM + i]; as_[i] = aubru[b * MM + i]; }
    __syncthreads();
    float binv = 1.f / beta_p[0];
    float ls2 = ls2_p[0];
    float w[9];
    #pragma unroll
    for (int k = 0; k < 9; ++k) w[k] = conv1_w[k];
    for (int c = tid; c < IMG; c += 256) {
        int y = c / PP, xq = c % PP;
        float dacc = 0.f;
        #pragma unroll
        for (int dy = 0; dy < 3; ++dy) {
            int yy = y + dy - 1;
            if ((unsigned)yy >= (unsigned)PP) continue;
            #pragma unroll
            for (int dx = 0; dx < 3; ++dx) {
                int xc = xq + dx - 1;
                if ((unsigned)xc >= (unsigned)PP) continue;
                dacc += xs[yy * PP + xc] * w[dy * 3 + dx];
            }
        }
        dacc = fmaxf(dacc, 0.f);
        const float* pt = PhiTW + (size_t)c * MM;
        float s1 = 0.f, s2 = 0.f;
        #pragma unroll 4
        for (int m = 0; m < MM; ++m) { float t = pt[m]; s1 += ps[m] * t; s2 += as_[m] * t; }
        int o = b * IMG + c;
        du[o] = dacc;
        duv[o] = dacc - v_in[o] * binv + ls2 * (PhiTb[o] - s1);
        wa[o] = s2;
    }
}

// ---------------- generic 3x3 same-pad conv, 4-pixel x-strip per thread
// epil: 0 none, 1 relu, 2 soft-threshold (thr_p)
__global__ __launch_bounds__(256) void k_conv3x3(
    const float* __restrict__ in, const float* __restrict__ w,
    const float* __restrict__ bias, const float* __restrict__ add,
    const float* __restrict__ thr_p, float* __restrict__ out,
    int Cin, int Cout, int epil, int total)
{
    int gid = blockIdx.x * 256 + threadIdx.x;
    if (gid >= total) return;
    int s = gid % 9; int t1 = gid / 9;
    int y = t1 % PP; int t2 = t1 / PP;
    int co = t2 % Cout; int b = t2 / Cout;
    int x0 = s * 4;
    float a0 = 0.f, a1 = 0.f, a2 = 0.f, a3 = 0.f;
    const float* wb = w + (size_t)co * Cin * 9;
    const float* ib = in + (size_t)b * Cin * IMG;
    for (int ci = 0; ci < Cin; ++ci) {
        const float* img = ib + ci * IMG;
        const float* wk = wb + ci * 9;
        #pragma unroll
        for (int dy = 0; dy < 3; ++dy) {
            int yy = y + dy - 1;
            if ((unsigned)yy >= (unsigned)PP) continue;
            const float* row = img + yy * PP;
            float wA = wk[dy * 3 + 0], wB = wk[dy * 3 + 1], wC = wk[dy * 3 + 2];
            float r0 = (x0 - 1 >= 0) ? row[x0 - 1] : 0.f;
            float r1 = row[x0];
            float r2 = (x0 + 1 < PP) ? row[x0 + 1] : 0.f;
            float r3 = (x0 + 2 < PP) ? row[x0 + 2] : 0.f;
            float r4 = (x0 + 3 < PP) ? row[x0 + 3] : 0.f;
            float r5 = (x0 + 4 < PP) ? row[x0 + 4] : 0.f;
            a0 += r0 * wA + r1 * wB + r2 * wC;
            a1 += r1 * wA + r2 * wB + r3 * wC;
            a2 += r2 * wA + r3 * wB + r4 * wC;
            a3 += r3 * wA + r4 * wB + r5 * wC;
        }
    }
    float bs = bias ? bias[co] : 0.f;
    float thr = (epil == 2) ? thr_p[0] : 0.f;
    float accs[4] = {a0, a1, a2, a3};
    int obase = (b * Cout + co) * IMG + y * PP;
    #pragma unroll
    for (int k = 0; k < 4; ++k) {
        int xk = x0 + k;
        if (xk >= PP) break;
        float vv = accs[k] + bs;
        if (add) vv += add[obase + xk];
        if (epil == 1) vv = fmaxf(vv, 0.f);
        else if (epil == 2) {
            float av = fabsf(vv) - thr;
            vv = (vv >= 0.f ? 1.f : -1.f) * fmaxf(av, 0.f);
        }
        out[obase + xk] = vv;
    }
}

// ---------------- duvw = beta*du - v - beta*x_pred
__global__ __launch_bounds__(256) void k_duvw(
    const float* __restrict__ du, const float* __restrict__ v_in,
    const float* __restrict__ xp, const float* __restrict__ beta_p,
    float* __restrict__ duvw, int total)
{
    int g = blockIdx.x * 256 + threadIdx.x;
    if (g >= total) return;
    float beta = beta_p[0];
    duvw[g] = beta * du[g] - v_in[g] - beta * xp[g];
}

// ---------------- d, uu2, rr, bn1a
__global__ __launch_bounds__(256) void k_rr(
    const float* __restrict__ duvww, const float* __restrict__ r_in,
    const float* __restrict__ x_in, const float* __restrict__ xx_in,
    const float* __restrict__ wa, const float* __restrict__ uu_in,
    const float* __restrict__ theta_p, const float* __restrict__ ls_p,
    const float* __restrict__ bn_g, const float* __restrict__ bn_b,
    float* __restrict__ rr, float* __restrict__ bn1a, int total)
{
    int g = blockIdx.x * 256 + threadIdx.x;
    if (g >= total) return;
    float theta = theta_p[0], ls = ls_p[0];
    float d = duvww[g] - r_in[g] + theta * (x_in[g] - xx_in[g]) + wa[g];
    float uu2 = uu_in[g] - ls * d;
    float rrv = uu2 - r_in[g] / theta;
    rr[g] = rrv;
    // 1/sqrt(1 + 1e-5)
    bn1a[g] = bn_g[0] * rrv * 0.9999950000374997f + bn_b[0];
}

// ---------------- b1/b2/b3 = 1x1 conv (64->16) + bias, written into zero-padded 39x39 buffers
__global__ __launch_bounds__(256) void k_b123(
    const float* __restrict__ rr3,
    const float* __restrict__ g_w, const float* __restrict__ g_b,
    const float* __restrict__ th_w, const float* __restrict__ th_b,
    const float* __restrict__ ph_w, const float* __restrict__ ph_b,
    float* __restrict__ b1p, float* __restrict__ b2p, float* __restrict__ b3p, int total)
{
    int g = blockIdx.x * 256 + threadIdx.x;
    if (g >= total) return;
    int j = g % IMG; int t = g / IMG; int o = t % 48; int b = t / 48;
    int sel = o / 16, co = o % 16;
    const float* w = sel == 0 ? g_w : (sel == 1 ? th_w : ph_w);
    const float* bi = sel == 0 ? g_b : (sel == 1 ? th_b : ph_b);
    float* outp = sel == 0 ? b1p : (sel == 1 ? b2p : b3p);
    const float* wr = w + co * 64;
    const float* ip = rr3 + (size_t)b * 64 * IMG + j;
    float acc = bi[co];
    #pragma unroll 8
    for (int ci = 0; ci < 64; ++ci) acc += ip[(size_t)ci * IMG] * wr[ci];
    int y = j / PP, xq = j % PP;
    outp[((size_t)(b * CATT + co) * PADW + y + 3) * PADW + (xq + 3)] = acc;
}

// ---------------- gather query patches: qg[b][p][c][49]
__global__ __launch_bounds__(256) void k_wi(
    const float* __restrict__ b1p, float* __restrict__ qg, int total)
{
    int g = blockIdx.x * 256 + threadIdx.x;
    if (g >= total) return;
    int k = g % KK2; int t = g / KK2; int c = t % CATT; int t2 = t / CATT;
    int p = t2 % NPATCH; int b = t2 / NPATCH;
    int ky = k / KK, kx = k % KK, py = p / NP1, px = p % NP1;
    qg[g] = b1p[((size_t)(b * CATT + c) * PADW + 4 * py + ky) * PADW + 4 * px + kx];
}

// ---------------- scores[b,p,pix] = <query p, key patch at pix>; thread=pixel, 27 p-accumulators
__global__ __launch_bounds__(256) void k_scores(
    const float* __restrict__ qg, const float* __restrict__ b3p,
    float* __restrict__ scores)
{
    int b = blockIdx.x / 5, t = blockIdx.x % 5;
    int pix = t * 256 + threadIdx.x;
    if (pix >= IMG) return;
    int p0 = blockIdx.y * SC_NP;
    int y = pix / PP, x = pix % PP;
    float acc[SC_NP];
    #pragma unroll
    for (int p = 0; p < SC_NP; ++p) acc[p] = 0.f;
    for (int c = 0; c < CATT; ++c) {
        const float* base = b3p + ((size_t)(b * CATT + c) * PADW + y) * PADW + x;
        float kv[KK2];
        #pragma unroll
        for (int ky = 0; ky < KK; ++ky)
            #pragma unroll
            for (int kx = 0; kx < KK; ++kx)
                kv[ky * KK + kx] = base[ky * PADW + kx];
        #pragma unroll
        for (int p = 0; p < SC_NP; ++p) {
            const float* q = qg + (size_t)((b * NPATCH + p0 + p) * CATT + c) * KK2;
            float a = acc[p];
            #pragma unroll
            for (int k = 0; k < KK2; ++k) a += q[k] * kv[k];
            acc[p] = a;
        }
    }
    #pragma unroll
    for (int p = 0; p < SC_NP; ++p)
        scores[(size_t)(b * NPATCH + p0 + p) * IMG + pix] = acc[p];
}

// ---------------- row softmax over 1089 (in-place), scale 10
__global__ __launch_bounds__(256) void k_softmax(float* __restrict__ sc)
{
    int row = blockIdx.x;
    float* p = sc + (size_t)row * IMG;
    __shared__ float red[256];
    int tid = threadIdx.x;
    float v[5];
    float m = -1e30f;
    #pragma unroll
    for (int i = 0; i < 5; ++i) {
        int idx = tid + i * 256;
        v[i] = (idx < IMG) ? p[idx] : -1e30f;
        m = fmaxf(m, v[i]);
    }
    red[tid] = m; __syncthreads();
    for (int s = 128; s > 0; s >>= 1) { if (tid < s) red[tid] = fmaxf(red[tid], red[tid + s]); __syncthreads(); }
    m = red[0]; __syncthreads();
    float sum = 0.f;
    #pragma unroll
    for (int i = 0; i < 5; ++i) {
        int idx = tid + i * 256;
        float e = (idx < IMG) ? __expf(10.f * (v[i] - m)) : 0.f;
        v[i] = e; sum += e;
    }
    red[tid] = sum; __syncthreads();
    for (int s = 128; s > 0; s >>= 1) { if (tid < s) red[tid] += red[tid + s]; __syncthreads(); }
    float inv = 1.f / red[0];
    #pragma unroll
    for (int i = 0; i < 5; ++i) {
        int idx = tid + i * 256;
        if (idx < IMG) p[idx] = v[i] * inv;
    }
}

// ---------------- agg[b,p,m] (m=(c,oy,ox)) = sum over 1089 of attn[p]*b2p shifted
__global__ __launch_bounds__(256) void k_agg(
    const float* __restrict__ attn, const float* __restrict__ b2p,
    float* __restrict__ agg)
{
    int b = blockIdx.x / 4, mt = blockIdx.x % 4;
    int m = mt * 256 + threadIdx.x;
    if (m >= 784) return;
    int p0 = blockIdx.y * AG_NP;
    int c = m / KK2; int r = m % KK2; int oy = r / KK, ox = r % KK;
    const float* v0 = b2p + ((size_t)(b * CATT + c) * PADW + oy) * PADW + ox;
    const float* ar = attn + (size_t)(b * NPATCH + p0) * IMG;
    float acc[AG_NP];
    #pragma unroll
    for (int p = 0; p < AG_NP; ++p) acc[p] = 0.f;
    for (int yy = 0; yy < PP; ++yy) {
        const float* vr = v0 + yy * PADW;
        const float* arow = ar + yy * PP;
        #pragma unroll 3
        for (int xxp = 0; xxp < PP; ++xxp) {
            float v = vr[xxp];
            #pragma unroll
            for (int p = 0; p < AG_NP; ++p) acc[p] += arow[(size_t)p * IMG + xxp] * v;
        }
    }
    #pragma unroll
    for (int p = 0; p < AG_NP; ++p)
        agg[(size_t)(b * NPATCH + p0 + p) * 784 + m] = acc[p];
}

// ---------------- fold (stride-4 overlap-add) + count normalize + crop -> y_att[b,c,33,33]
__global__ __launch_bounds__(256) void k_fold(
    const float* __restrict__ agg, float* __restrict__ y_att, int total)
{
    int g = blockIdx.x * 256 + threadIdx.x;
    if (g >= total) return;
    int j = g % IMG; int t = g / IMG; int c = t % CATT; int b = t / CATT;
    int y = j / PP, x = j % PP;
    int yp = y + 3, xp = x + 3;
    int pylo = (yp - 3) >> 2; int pyhi = min(8, yp >> 2);
    int pxlo = (xp - 3) >> 2; int pxhi = min(8, xp >> 2);
    float sum = 0.f;
    int cnt = (pyhi - pylo + 1) * (pxhi - pxlo + 1);
    for (int py = pylo; py <= pyhi; ++py) {
        int ky = yp - 4 * py;
        for (int px = pxlo; px <= pxhi; ++px) {
            int kx = xp - 4 * px;
            sum += agg[(size_t)(b * NPATCH + py * NP1 + px) * 784 + c * KK2 + ky * KK + kx];
        }
    }
    y_att[(size_t)(b * CATT + c) * IMG + j] = sum / (float)cnt;
}

// ---------------- 1x1 conv generic (used for W: 16->64, +bias, +rr3 residual)
__global__ __launch_bounds__(256) void k_conv1x1(
    const float* __restrict__ in, const float* __restrict__ w,
    const float* __restrict__ bias, const float* __restrict__ add,
    float* __restrict__ out, int Cin, int Cout, int total)
{
    int g = blockIdx.x * 256 + threadIdx.x;
    if (g >= total) return;
    int j = g % IMG; int t = g / IMG; int co = t % Cout; int b = t / Cout;
    const float* ip = in + (size_t)b * Cin * IMG + j;
    const float* wr = w + co * Cin;
    float acc = bias ? bias[co] : 0.f;
    #pragma unroll 4
    for (int ci = 0; ci < Cin; ++ci) acc += ip[(size_t)ci * IMG] * wr[ci];
    if (add) acc += add[g];
    out[g] = acc;
}

extern "C" void kernel_launch(void* const* d_in, const int* in_sizes, int n_in,
                              void* d_out, int out_size, void* d_ws, size_t ws_size,
                              hipStream_t stream)
{
    (void)in_sizes; (void)n_in; (void)out_size; (void)ws_size;
    const float* x      = (const float*)d_in[0];
    const float* PhiTb  = (const float*)d_in[1];
    const float* v_in   = (const float*)d_in[2];
    const float* r_in   = (const float*)d_in[3];
    const float* ru     = (const float*)d_in[4];
    const float* xx_in  = (const float*)d_in[5];
    const float* uu_in  = (const float*)d_in[6];
    const float* Phix   = (const float*)d_in[7];
    const float* PhiW   = (const float*)d_in[8];
    const float* PhiTW  = (const float*)d_in[9];
    const float* ls_p   = (const float*)d_in[10];
    const float* ls2_p  = (const float*)d_in[11];
    const float* thr_p  = (const float*)d_in[12];
    const float* beta_p = (const float*)d_in[13];
    const float* mu_p   = (const float*)d_in[14];
    const float* theta_p= (const float*)d_in[15];
    const float* conv1_w  = (const float*)d_in[16];
    const float* conv2_w  = (const float*)d_in[17];
    const float* convG1_w = (const float*)d_in[18];
    const float* convD_w  = (const float*)d_in[19];
    const float* conv1f_w = (const float*)d_in[20];
    const float* conv2f_w = (const float*)d_in[21];
    const float* conv1b_w = (const float*)d_in[22];
    const float* conv2b_w = (const float*)d_in[23];
    const float* convG_w  = (const float*)d_in[24];
    const float* convG2_w = (const float*)d_in[25];
    const float* head_w = (const float*)d_in[26];
    const float* head_b = (const float*)d_in[27];
    const float* tail_w = (const float*)d_in[28];
    const float* tail_b = (const float*)d_in[29];
    const float* rb1_w1 = (const float*)d_in[30];
    const float* rb1_b1 = (const float*)d_in[31];
    const float* rb1_w2 = (const float*)d_in[32];
    const float* rb1_b2 = (const float*)d_in[33];
    const float* rb2_w1 = (const float*)d_in[34];
    const float* rb2_b1 = (const float*)d_in[35];
    const float* rb2_w2 = (const float*)d_in[36];
    const float* rb2_b2 = (const float*)d_in[37];
    const float* g_w  = (const float*)d_in[38];
    const float* g_b  = (const float*)d_in[39];
    const float* th_w = (const float*)d_in[40];
    const float* th_b = (const float*)d_in[41];
    const float* ph_w = (const float*)d_in[42];
    const float* ph_b = (const float*)d_in[43];
    const float* W_w  = (const float*)d_in[44];
    const float* W_b  = (const float*)d_in[45];
    const float* bn_g = (const float*)d_in[46];
    const float* bn_b = (const float*)d_in[47];

    const int NSM = BB * IMG;            // 69696
    float* ws = (float*)d_ws;
    float* du    = ws;
    float* Phi_x = du + NSM;
    float* aubru = Phi_x + BB * MM;
    float* duv   = aubru + BB * MM;
    float* wa    = duv + NSM;
    float* duvw  = wa + NSM;
    float* rr    = duvw + NSM;
    float* bn1a  = rr + NSM;
    float* rr_nl = bn1a + NSM;
    float* xp    = rr_nl + NSM;
    float* duvww = xp + NSM;
    float* rr3   = duvww + NSM;                        // B*64*IMG
    float* R7    = rr3 + (size_t)BB * 64 * IMG;        // buf_a|buf_b, reused as qg, then agg
    float* buf_a = R7;
    float* buf_b = R7 + (size_t)BB * 32 * IMG;
    float* qg    = R7;
    float* agg   = R7;
    float* b1p   = R7 + (size_t)2 * BB * 32 * IMG;     // padded 39x39 x16ch
    float* b2p   = b1p + (size_t)BB * CATT * PIMG;
    float* b3p   = b2p + (size_t)BB * CATT * PIMG;
    float* y_att = b1p;                                 // reuse (b1p dead after k_wi)
    float* scores= b3p + (size_t)BB * CATT * PIMG;      // B*81*IMG
    float* ybuf  = scores;                              // reuse (attn dead after k_agg)

    const int tot32 = BB * 32 * PP * 9;   // strip-conv threads, Cout=32
    const int tot64 = BB * 64 * PP * 9;
    const int tot1  = BB * 1  * PP * 9;

    // zero the padded b1p/b2p/b3p region (borders must be 0; ws is poisoned each call)
    hipMemsetAsync(b1p, 0, (size_t)3 * BB * CATT * PIMG * sizeof(float), stream);

    k_phi<<<BB, 256, 0, stream>>>(x, PhiW, Phix, ru, mu_p, Phi_x, aubru);
    k_duv<<<BB, 256, 0, stream>>>(x, v_in, PhiTb, PhiTW, Phi_x, aubru, conv1_w, beta_p, ls2_p, du, duv, wa);

    // denoiser: head + 2 resblocks + tail
    k_conv3x3<<<cdiv_i(tot32,256),256,0,stream>>>(duv,  head_w, head_b, nullptr, nullptr, buf_a, 1, 32, 0, tot32);
    k_conv3x3<<<cdiv_i(tot32,256),256,0,stream>>>(buf_a, rb1_w1, rb1_b1, nullptr, nullptr, buf_b, 32, 32, 1, tot32);
    k_conv3x3<<<cdiv_i(tot32,256),256,0,stream>>>(buf_b, rb1_w2, rb1_b2, buf_a,  nullptr, buf_a, 32, 32, 0, tot32);
    k_conv3x3<<<cdiv_i(tot32,256),256,0,stream>>>(buf_a, rb2_w1, rb2_b1, nullptr, nullptr, buf_b, 32, 32, 1, tot32);
    k_conv3x3<<<cdiv_i(tot32,256),256,0,stream>>>(buf_b, rb2_w2, rb2_b2, buf_a,  nullptr, buf_a, 32, 32, 0, tot32);
    k_conv3x3<<<cdiv_i(tot1,256),256,0,stream>>>(buf_a, tail_w, tail_b, duv, nullptr, xp, 32, 1, 0, tot1); // xp = x_pred

    k_duvw<<<cdiv_i(NSM,256),256,0,stream>>>(du, v_in, xp, beta_p, duvw, NSM);
    k_conv3x3<<<cdiv_i(tot1,256),256,0,stream>>>(duvw, conv2_w, nullptr, nullptr, nullptr, duvww, 1, 1, 1, tot1);
    k_rr<<<cdiv_i(NSM,256),256,0,stream>>>(duvww, r_in, x, xx_in, wa, uu_in, theta_p, ls_p, bn_g, bn_b, rr, bn1a, NSM);
    k_conv3x3<<<cdiv_i(tot64,256),256,0,stream>>>(bn1a, convG1_w, nullptr, nullptr, nullptr, rr3, 1, 64, 1, tot64);

    // attention
    k_b123<<<cdiv_i(BB*48*IMG,256),256,0,stream>>>(rr3, g_w, g_b, th_w, th_b, ph_w, ph_b, b1p, b2p, b3p, BB*48*IMG);
    k_wi<<<cdiv_i(BB*NPATCH*CATT*KK2,256),256,0,stream>>>(b1p, qg, BB*NPATCH*CATT*KK2);
    {
        dim3 gs(BB * 5, 3);
        k_scores<<<gs, 256, 0, stream>>>(qg, b3p, scores);
    }
    k_softmax<<<BB * NPATCH, 256, 0, stream>>>(scores);
    {
        dim3 ga(BB * 4, 3);
        k_agg<<<ga, 256, 0, stream>>>(scores, b2p, agg);
    }
    k_fold<<<cdiv_i(BB*CATT*IMG,256),256,0,stream>>>(agg, y_att, BB*CATT*IMG);
    k_conv1x1<<<cdiv_i(BB*64*IMG,256),256,0,stream>>>(y_att, W_w, W_b, rr3, ybuf, 16, 64, BB*64*IMG);
    k_conv3x3<<<cdiv_i(tot1,256),256,0,stream>>>(ybuf, convG2_w, nullptr, rr, nullptr, rr_nl, 64, 1, 0, tot1);

    // ISTA soft-threshold stage
    k_conv3x3<<<cdiv_i(tot32,256),256,0,stream>>>(rr_nl, convD_w,  nullptr, nullptr, nullptr, buf_a, 1, 32, 0, tot32);
    k_conv3x3<<<cdiv_i(tot32,256),256,0,stream>>>(buf_a, conv1f_w, nullptr, nullptr, nullptr, buf_b, 32, 32, 1, tot32);
    k_conv3x3<<<cdiv_i(tot32,256),256,0,stream>>>(buf_b, conv2f_w, nullptr, nullptr, thr_p,   buf_a, 32, 32, 2, tot32);
    k_conv3x3<<<cdiv_i(tot32,256),256,0,stream>>>(buf_a, conv1b_w, nullptr, nullptr, nullptr, buf_b, 32, 32, 1, tot32);
    k_conv3x3<<<cdiv_i(tot32,256),256,0,stream>>>(buf_b, conv2b_w, nullptr, nullptr, nullptr, buf_a, 32, 32, 0, tot32);
    k_conv3x3<<<cdiv_i(tot1,256),256,0,stream>>>(buf_a, convG_w, nullptr, rr_nl, nullptr, (float*)d_out, 32, 1, 0, tot1);
}

// Round 2
// 3389.926 us; speedup vs baseline: 1.0126x; 1.0126x over previous
//
#include <hip/hip_runtime.h>

#define BB 64
#define PP 33
#define IMG 1089        // 33*33
#define MM 272
#define NP1 9
#define NPATCH 81
#define KK 7
#define KK2 49
#define CATT 16
#define PADW 39
#define PIMG 1521       // 39*39

static __host__ __device__ inline int cdiv_i(int a, int b) { return (a + b - 1) / b; }

// ---------------- generic 32x32 tiled transpose: in[R][C] -> out[C][R]
__global__ __launch_bounds__(256) void k_tr(
    const float* __restrict__ in, float* __restrict__ out, int R, int C)
{
    __shared__ float t[32][33];
    int c0 = blockIdx.x * 32, r0 = blockIdx.y * 32;
    int tx = threadIdx.x, ty = threadIdx.y;
    for (int i = ty; i < 32; i += 8) {
        int r = r0 + i, c = c0 + tx;
        if (r < R && c < C) t[i][tx] = in[(size_t)r * C + c];
    }
    __syncthreads();
    for (int i = ty; i < 32; i += 8) {
        int c = c0 + i, r = r0 + tx;
        if (c < C && r < R) out[(size_t)c * R + r] = t[tx][i];
    }
}

// ---------------- Phi forward (coalesced via PhiWT[j][m]): Phi_x[b,m], aubru
__global__ __launch_bounds__(320) void k_phi(
    const float* __restrict__ x, const float* __restrict__ PhiWT,
    const float* __restrict__ Phix_in, const float* __restrict__ ru,
    const float* __restrict__ mu_p,
    float* __restrict__ Phi_x, float* __restrict__ aubru)
{
    int b = blockIdx.x, tid = threadIdx.x;
    __shared__ float xs[IMG];
    for (int i = tid; i < IMG; i += 320) xs[i] = x[b * IMG + i];
    __syncthreads();
    if (tid >= MM) return;
    float mu = mu_p[0];
    const float* w = PhiWT + tid;
    float acc = 0.f;
    #pragma unroll 4
    for (int j = 0; j < IMG; ++j) acc += xs[j] * w[(size_t)j * MM];
    Phi_x[b * MM + tid] = acc;
    aubru[b * MM + tid] = mu * (acc - Phix_in[b * MM + tid]) - ru[b * MM + tid];
}

// ---------------- du, duv, wa (coalesced via PhiTWT[m][c])
__global__ __launch_bounds__(256) void k_duv(
    const float* __restrict__ x, const float* __restrict__ v_in,
    const float* __restrict__ PhiTb, const float* __restrict__ PhiTWT,
    const float* __restrict__ Phi_x, const float* __restrict__ aubru,
    const float* __restrict__ conv1_w,
    const float* __restrict__ beta_p, const float* __restrict__ ls2_p,
    float* __restrict__ du, float* __restrict__ duv, float* __restrict__ wa)
{
    int b = blockIdx.y, tid = threadIdx.x;
    __shared__ float xs[IMG];
    __shared__ float ps[MM], as_[MM];
    for (int i = tid; i < IMG; i += 256) xs[i] = x[b * IMG + i];
    for (int i = tid; i < MM; i += 256) { ps[i] = Phi_x[b * MM + i]; as_[i] = aubru[b * MM + i]; }
    __syncthreads();
    int c = blockIdx.x * 256 + tid;
    if (c >= IMG) return;
    float binv = 1.f / beta_p[0];
    float ls2 = ls2_p[0];
    int y = c / PP, xq = c % PP;
    float dacc = 0.f;
    #pragma unroll
    for (int dy = 0; dy < 3; ++dy) {
        int yy = y + dy - 1;
        if ((unsigned)yy >= (unsigned)PP) continue;
        #pragma unroll
        for (int dx = 0; dx < 3; ++dx) {
            int xc = xq + dx - 1;
            if ((unsigned)xc >= (unsigned)PP) continue;
            dacc += xs[yy * PP + xc] * conv1_w[dy * 3 + dx];
        }
    }
    dacc = fmaxf(dacc, 0.f);
    const float* pt = PhiTWT + c;
    float s1 = 0.f, s2 = 0.f;
    #pragma unroll 4
    for (int m = 0; m < MM; ++m) {
        float t = pt[(size_t)m * IMG];
        s1 += ps[m] * t; s2 += as_[m] * t;
    }
    int o = b * IMG + c;
    du[o] = dacc;
    duv[o] = dacc - v_in[o] * binv + ls2 * (PhiTb[o] - s1);
    wa[o] = s2;
}

// ---------------- generic 3x3 same-pad conv, 4-pixel x-strip per thread
__global__ __launch_bounds__(256) void k_conv3x3(
    const float* __restrict__ in, const float* __restrict__ w,
    const float* __restrict__ bias, const float* __restrict__ add,
    const float* __restrict__ thr_p, float* __restrict__ out,
    int Cin, int Cout, int epil, int total)
{
    int gid = blockIdx.x * 256 + threadIdx.x;
    if (gid >= total) return;
    int s = gid % 9; int t1 = gid / 9;
    int y = t1 % PP; int t2 = t1 / PP;
    int co = t2 % Cout; int b = t2 / Cout;
    int x0 = s * 4;
    float a0 = 0.f, a1 = 0.f, a2 = 0.f, a3 = 0.f;
    const float* wb = w + (size_t)co * Cin * 9;
    const float* ib = in + (size_t)b * Cin * IMG;
    for (int ci = 0; ci < Cin; ++ci) {
        const float* img = ib + ci * IMG;
        const float* wk = wb + ci * 9;
        #pragma unroll
        for (int dy = 0; dy < 3; ++dy) {
            int yy = y + dy - 1;
            if ((unsigned)yy >= (unsigned)PP) continue;
            const float* row = img + yy * PP;
            float wA = wk[dy * 3 + 0], wB = wk[dy * 3 + 1], wC = wk[dy * 3 + 2];
            float r0 = (x0 - 1 >= 0) ? row[x0 - 1] : 0.f;
            float r1 = row[x0];
            float r2 = (x0 + 1 < PP) ? row[x0 + 1] : 0.f;
            float r3 = (x0 + 2 < PP) ? row[x0 + 2] : 0.f;
            float r4 = (x0 + 3 < PP) ? row[x0 + 3] : 0.f;
            float r5 = (x0 + 4 < PP) ? row[x0 + 4] : 0.f;
            a0 += r0 * wA + r1 * wB + r2 * wC;
            a1 += r1 * wA + r2 * wB + r3 * wC;
            a2 += r2 * wA + r3 * wB + r4 * wC;
            a3 += r3 * wA + r4 * wB + r5 * wC;
        }
    }
    float bs = bias ? bias[co] : 0.f;
    float thr = (epil == 2) ? thr_p[0] : 0.f;
    float accs[4] = {a0, a1, a2, a3};
    int obase = (b * Cout + co) * IMG + y * PP;
    #pragma unroll
    for (int k = 0; k < 4; ++k) {
        int xk = x0 + k;
        if (xk >= PP) break;
        float vv = accs[k] + bs;
        if (add) vv += add[obase + xk];
        if (epil == 1) vv = fmaxf(vv, 0.f);
        else if (epil == 2) {
            float av = fabsf(vv) - thr;
            vv = (vv >= 0.f ? 1.f : -1.f) * fmaxf(av, 0.f);
        }
        out[obase + xk] = vv;
    }
}

// ---------------- duvw = beta*du - v - beta*x_pred
__global__ __launch_bounds__(256) void k_duvw(
    const float* __restrict__ du, const float* __restrict__ v_in,
    const float* __restrict__ xp, const float* __restrict__ beta_p,
    float* __restrict__ duvw, int total)
{
    int g = blockIdx.x * 256 + threadIdx.x;
    if (g >= total) return;
    float beta = beta_p[0];
    duvw[g] = beta * du[g] - v_in[g] - beta * xp[g];
}

// ---------------- d, uu2, rr, bn1a
__global__ __launch_bounds__(256) void k_rr(
    const float* __restrict__ duvww, const float* __restrict__ r_in,
    const float* __restrict__ x_in, const float* __restrict__ xx_in,
    const float* __restrict__ wa, const float* __restrict__ uu_in,
    const float* __restrict__ theta_p, const float* __restrict__ ls_p,
    const float* __restrict__ bn_g, const float* __restrict__ bn_b,
    float* __restrict__ rr, float* __restrict__ bn1a, int total)
{
    int g = blockIdx.x * 256 + threadIdx.x;
    if (g >= total) return;
    float theta = theta_p[0], ls = ls_p[0];
    float d = duvww[g] - r_in[g] + theta * (x_in[g] - xx_in[g]) + wa[g];
    float uu2 = uu_in[g] - ls * d;
    float rrv = uu2 - r_in[g] / theta;
    rr[g] = rrv;
    bn1a[g] = bn_g[0] * rrv * 0.9999950000374997f + bn_b[0];
}

// ---------------- b1/b2/b3 = 1x1 conv (64->16) + bias into zero-padded 39x39
__global__ __launch_bounds__(256) void k_b123(
    const float* __restrict__ rr3,
    const float* __restrict__ g_w, const float* __restrict__ g_b,
    const float* __restrict__ th_w, const float* __restrict__ th_b,
    const float* __restrict__ ph_w, const float* __restrict__ ph_b,
    float* __restrict__ b1p, float* __restrict__ b2p, float* __restrict__ b3p, int total)
{
    int g = blockIdx.x * 256 + threadIdx.x;
    if (g >= total) return;
    int j = g % IMG; int t = g / IMG; int o = t % 48; int b = t / 48;
    int sel = o / 16, co = o % 16;
    const float* w = sel == 0 ? g_w : (sel == 1 ? th_w : ph_w);
    const float* bi = sel == 0 ? g_b : (sel == 1 ? th_b : ph_b);
    float* outp = sel == 0 ? b1p : (sel == 1 ? b2p : b3p);
    const float* wr = w + co * 64;
    const float* ip = rr3 + (size_t)b * 64 * IMG + j;
    float acc = bi[co];
    #pragma unroll 8
    for (int ci = 0; ci < 64; ++ci) acc += ip[(size_t)ci * IMG] * wr[ci];
    int y = j / PP, xq = j % PP;
    outp[((size_t)(b * CATT + co) * PADW + y + 3) * PADW + (xq + 3)] = acc;
}

// ---------------- scores: LDS-staged q (float4 broadcast), 2 pixels/thread, 28-p groups
// grid: (64*5, 3), block 128.  scores[b,p,pix] = <query p, key patch at pix>
__global__ __launch_bounds__(128) void k_scores(
    const float* __restrict__ b1p, const float* __restrict__ b3p,
    float* __restrict__ scores)
{
    __shared__ float qs[KK2][28];
    int b = blockIdx.x / 5, chunk = blockIdx.x % 5;
    int p0 = blockIdx.y * 28;
    int tid = threadIdx.x;

    int pixA = chunk * 128 + tid;            // [0, 640)
    int validA = pixA < 545;
    int validB = pixA < 544;
    int pixB = validB ? pixA + 545 : pixA;   // clamp keeps loads in-bounds
    int yA = pixA < IMG ? pixA / PP : 0, xA = pixA < IMG ? pixA % PP : 0;
    int yB = pixB / PP, xB = pixB % PP;

    float accA[28], accB[28];
    #pragma unroll
    for (int i = 0; i < 28; ++i) { accA[i] = 0.f; accB[i] = 0.f; }

    for (int c = 0; c < CATT; ++c) {
        __syncthreads();
        // stage q for this channel: qs[k][pp] = b1p patch value (0 for pad p)
        for (int idx = tid; idx < KK2 * 28; idx += 128) {
            int k = idx / 28, pp = idx % 28;
            int p = p0 + pp;
            float v = 0.f;
            if (p < NPATCH) {
                int py = p / NP1, px = p % NP1;
                int row = 4 * py + k / KK, col = 4 * px + k % KK;
                v = b1p[((size_t)(b * CATT + c) * PADW + row) * PADW + col];
            }
            qs[k][pp] = v;
        }
        __syncthreads();
        const float* plane = b3p + (size_t)(b * CATT + c) * PIMG;
        #pragma unroll
        for (int ky = 0; ky < KK; ++ky) {
            const float* baseA = plane + (yA + ky) * PADW + xA;
            const float* baseB = plane + (yB + ky) * PADW + xB;
            float rA[KK], rB[KK];
            #pragma unroll
            for (int i = 0; i < KK; ++i) { rA[i] = baseA[i]; rB[i] = baseB[i]; }
            #pragma unroll
            for (int kx = 0; kx < KK; ++kx) {
                int k = ky * KK + kx;
                const float4* q4 = (const float4*)(&qs[k][0]);
                float a = rA[kx], bb = rB[kx];
                #pragma unroll
                for (int pq = 0; pq < 7; ++pq) {
                    float4 q = q4[pq];
                    accA[pq * 4 + 0] += q.x * a;  accB[pq * 4 + 0] += q.x * bb;
                    accA[pq * 4 + 1] += q.y * a;  accB[pq * 4 + 1] += q.y * bb;
                    accA[pq * 4 + 2] += q.z * a;  accB[pq * 4 + 2] += q.z * bb;
                    accA[pq * 4 + 3] += q.w * a;  accB[pq * 4 + 3] += q.w * bb;
                }
            }
        }
    }
    #pragma unroll
    for (int pp = 0; pp < 28; ++pp) {
        int p = p0 + pp;
        if (p >= NPATCH) break;
        size_t rowb = (size_t)(b * NPATCH + p) * IMG;
        if (validA) scores[rowb + pixA] = accA[pp];
        if (validB) scores[rowb + pixA + 545] = accB[pp];
    }
}

// ---------------- row softmax over 1089 (in-place), scale 10
__global__ __launch_bounds__(256) void k_softmax(float* __restrict__ sc)
{
    int row = blockIdx.x;
    float* p = sc + (size_t)row * IMG;
    __shared__ float red[256];
    int tid = threadIdx.x;
    float v[5];
    float m = -1e30f;
    #pragma unroll
    for (int i = 0; i < 5; ++i) {
        int idx = tid + i * 256;
        v[i] = (idx < IMG) ? p[idx] : -1e30f;
        m = fmaxf(m, v[i]);
    }
    red[tid] = m; __syncthreads();
    for (int s = 128; s > 0; s >>= 1) { if (tid < s) red[tid] = fmaxf(red[tid], red[tid + s]); __syncthreads(); }
    m = red[0]; __syncthreads();
    float sum = 0.f;
    #pragma unroll
    for (int i = 0; i < 5; ++i) {
        int idx = tid + i * 256;
        float e = (idx < IMG) ? __expf(10.f * (v[i] - m)) : 0.f;
        v[i] = e; sum += e;
    }
    red[tid] = sum; __syncthreads();
    for (int s = 128; s > 0; s >>= 1) { if (tid < s) red[tid] += red[tid + s]; __syncthreads(); }
    float inv = 1.f / red[0];
    #pragma unroll
    for (int i = 0; i < 5; ++i) {
        int idx = tid + i * 256;
        if (idx < IMG) p[idx] = v[i] * inv;
    }
}

// ---------------- agg: output-stationary (p,c) thread holds 7x7 acc, atomic 3-way y-split
// grid: (64, 3, 6) block 256 = 32p x 8c.  z = ythird*2 + chalf
__global__ __launch_bounds__(256) void k_agg(
    const float* __restrict__ attn, const float* __restrict__ b2p,
    float* __restrict__ agg)
{
    int b = blockIdx.x;
    int p = blockIdx.y * 32 + (threadIdx.x & 31);
    int ythird = blockIdx.z >> 1;
    int c = (blockIdx.z & 1) * 8 + (threadIdx.x >> 5);
    if (p >= NPATCH) return;
    const float* ap = attn + (size_t)(b * NPATCH + p) * IMG;
    const float* vp = b2p + (size_t)(b * CATT + c) * PIMG;
    float acc[KK2];
    #pragma unroll
    for (int k = 0; k < KK2; ++k) acc[k] = 0.f;
    int y0 = ythird * 11;
    for (int y = y0; y < y0 + 11; ++y) {
        const float* ar = ap + y * PP;
        const float* vr = vp + y * PADW;
        #pragma unroll
        for (int x = 0; x < PP; ++x) {
            float a = ar[x];
            #pragma unroll
            for (int oy = 0; oy < KK; ++oy)
                #pragma unroll
                for (int ox = 0; ox < KK; ++ox)
                    acc[oy * KK + ox] += a * vr[oy * PADW + x + ox];
        }
    }
    float* op = agg + (size_t)((b * NPATCH + p) * CATT + c) * KK2;
    #pragma unroll
    for (int k = 0; k < KK2; ++k) atomicAdd(&op[k], acc[k]);
}

// ---------------- fold + count normalize + crop -> y_att[b,c,33,33]
__global__ __launch_bounds__(256) void k_fold(
    const float* __restrict__ agg, float* __restrict__ y_att, int total)
{
    int g = blockIdx.x * 256 + threadIdx.x;
    if (g >= total) return;
    int j = g % IMG; int t = g / IMG; int c = t % CATT; int b = t / CATT;
    int y = j / PP, x = j % PP;
    int yp = y + 3, xp = x + 3;
    int pylo = (yp - 3) >> 2; int pyhi = min(8, yp >> 2);
    int pxlo = (xp - 3) >> 2; int pxhi = min(8, xp >> 2);
    float sum = 0.f;
    int cnt = (pyhi - pylo + 1) * (pxhi - pxlo + 1);
    for (int py = pylo; py <= pyhi; ++py) {
        int ky = yp - 4 * py;
        for (int px = pxlo; px <= pxhi; ++px) {
            int kx = xp - 4 * px;
            sum += agg[(size_t)((b * NPATCH + py * NP1 + px) * CATT + c) * KK2 + ky * KK + kx];
        }
    }
    y_att[(size_t)(b * CATT + c) * IMG + j] = sum / (float)cnt;
}

// ---------------- 1x1 conv generic (W: 16->64, +bias, +rr3 residual)
__global__ __launch_bounds__(256) void k_conv1x1(
    const float* __restrict__ in, const float* __restrict__ w,
    const float* __restrict__ bias, const float* __restrict__ add,
    float* __restrict__ out, int Cin, int Cout, int total)
{
    int g = blockIdx.x * 256 + threadIdx.x;
    if (g >= total) return;
    int j = g % IMG; int t = g / IMG; int co = t % Cout; int b = t / Cout;
    const float* ip = in + (size_t)b * Cin * IMG + j;
    const float* wr = w + co * Cin;
    float acc = bias ? bias[co] : 0.f;
    #pragma unroll 4
    for (int ci = 0; ci < Cin; ++ci) acc += ip[(size_t)ci * IMG] * wr[ci];
    if (add) acc += add[g];
    out[g] = acc;
}

extern "C" void kernel_launch(void* const* d_in, const int* in_sizes, int n_in,
                              void* d_out, int out_size, void* d_ws, size_t ws_size,
                              hipStream_t stream)
{
    (void)in_sizes; (void)n_in; (void)out_size; (void)ws_size;
    const float* x      = (const float*)d_in[0];
    const float* PhiTb  = (const float*)d_in[1];
    const float* v_in   = (const float*)d_in[2];
    const float* r_in   = (const float*)d_in[3];
    const float* ru     = (const float*)d_in[4];
    const float* xx_in  = (const float*)d_in[5];
    const float* uu_in  = (const float*)d_in[6];
    const float* Phix   = (const float*)d_in[7];
    const float* PhiW   = (const float*)d_in[8];
    const float* PhiTW  = (const float*)d_in[9];
    const float* ls_p   = (const float*)d_in[10];
    const float* ls2_p  = (const float*)d_in[11];
    const float* thr_p  = (const float*)d_in[12];
    const float* beta_p = (const float*)d_in[13];
    const float* mu_p   = (const float*)d_in[14];
    const float* theta_p= (const float*)d_in[15];
    const float* conv1_w  = (const float*)d_in[16];
    const float* conv2_w  = (const float*)d_in[17];
    const float* convG1_w = (const float*)d_in[18];
    const float* convD_w  = (const float*)d_in[19];
    const float* conv1f_w = (const float*)d_in[20];
    const float* conv2f_w = (const float*)d_in[21];
    const float* conv1b_w = (const float*)d_in[22];
    const float* conv2b_w = (const float*)d_in[23];
    const float* convG_w  = (const float*)d_in[24];
    const float* convG2_w = (const float*)d_in[25];
    const float* head_w = (const float*)d_in[26];
    const float* head_b = (const float*)d_in[27];
    const float* tail_w = (const float*)d_in[28];
    const float* tail_b = (const float*)d_in[29];
    const float* rb1_w1 = (const float*)d_in[30];
    const float* rb1_b1 = (const float*)d_in[31];
    const float* rb1_w2 = (const float*)d_in[32];
    const float* rb1_b2 = (const float*)d_in[33];
    const float* rb2_w1 = (const float*)d_in[34];
    const float* rb2_b1 = (const float*)d_in[35];
    const float* rb2_w2 = (const float*)d_in[36];
    const float* rb2_b2 = (const float*)d_in[37];
    const float* g_w  = (const float*)d_in[38];
    const float* g_b  = (const float*)d_in[39];
    const float* th_w = (const float*)d_in[40];
    const float* th_b = (const float*)d_in[41];
    const float* ph_w = (const float*)d_in[42];
    const float* ph_b = (const float*)d_in[43];
    const float* W_w  = (const float*)d_in[44];
    const float* W_b  = (const float*)d_in[45];
    const float* bn_g = (const float*)d_in[46];
    const float* bn_b = (const float*)d_in[47];

    const int NSM = BB * IMG;            // 69696
    float* ws = (float*)d_ws;
    float* du    = ws;
    float* Phi_x = du + NSM;
    float* aubru = Phi_x + BB * MM;
    float* duv   = aubru + BB * MM;
    float* wa    = duv + NSM;
    float* duvw  = wa + NSM;
    float* rr    = duvw + NSM;
    float* bn1a  = rr + NSM;
    float* rr_nl = bn1a + NSM;
    float* xp    = rr_nl + NSM;
    float* duvww = xp + NSM;
    float* rr3   = duvww + NSM;                        // B*64*IMG
    float* R7    = rr3 + (size_t)BB * 64 * IMG;        // buf_a|buf_b; reused as agg
    float* buf_a = R7;
    float* buf_b = R7 + (size_t)BB * 32 * IMG;
    float* agg   = R7;                                  // 64*81*784 = 4.06M floats < 4.46M
    float* b1p   = R7 + (size_t)2 * BB * 32 * IMG;     // padded 39x39 x16ch
    float* b2p   = b1p + (size_t)BB * CATT * PIMG;
    float* b3p   = b2p + (size_t)BB * CATT * PIMG;
    float* y_att = b1p;                                 // reuse (b1p dead after k_scores)
    float* scores= b3p + (size_t)BB * CATT * PIMG;      // B*81*IMG
    float* ybuf  = scores;                              // reuse (attn dead after k_agg)
    float* PhiWT = scores + (size_t)BB * NPATCH * IMG;  // [1089][272]
    float* PhiTWT= PhiWT + (size_t)MM * IMG;            // [272][1089]

    const int tot32 = BB * 32 * PP * 9;
    const int tot64 = BB * 64 * PP * 9;
    const int tot1  = BB * 1  * PP * 9;

    // zero padded b1p/b2p/b3p (borders must be 0; ws re-poisoned each call)
    hipMemsetAsync(b1p, 0, (size_t)3 * BB * CATT * PIMG * sizeof(float), stream);

    // transpose measurement operators (once per call; capture-safe)
    {
        dim3 blk(32, 8);
        dim3 g1(cdiv_i(IMG, 32), cdiv_i(MM, 32));   // PhiW[272][1089] -> PhiWT[1089][272]
        k_tr<<<g1, blk, 0, stream>>>(PhiW, PhiWT, MM, IMG);
        dim3 g2(cdiv_i(MM, 32), cdiv_i(IMG, 32));   // PhiTW[1089][272] -> PhiTWT[272][1089]
        k_tr<<<g2, blk, 0, stream>>>(PhiTW, PhiTWT, IMG, MM);
    }

    k_phi<<<BB, 320, 0, stream>>>(x, PhiWT, Phix, ru, mu_p, Phi_x, aubru);
    {
        dim3 gd(cdiv_i(IMG, 256), BB);
        k_duv<<<gd, 256, 0, stream>>>(x, v_in, PhiTb, PhiTWT, Phi_x, aubru, conv1_w, beta_p, ls2_p, du, duv, wa);
    }

    // denoiser: head + 2 resblocks + tail
    k_conv3x3<<<cdiv_i(tot32,256),256,0,stream>>>(duv,  head_w, head_b, nullptr, nullptr, buf_a, 1, 32, 0, tot32);
    k_conv3x3<<<cdiv_i(tot32,256),256,0,stream>>>(buf_a, rb1_w1, rb1_b1, nullptr, nullptr, buf_b, 32, 32, 1, tot32);
    k_conv3x3<<<cdiv_i(tot32,256),256,0,stream>>>(buf_b, rb1_w2, rb1_b2, buf_a,  nullptr, buf_a, 32, 32, 0, tot32);
    k_conv3x3<<<cdiv_i(tot32,256),256,0,stream>>>(buf_a, rb2_w1, rb2_b1, nullptr, nullptr, buf_b, 32, 32, 1, tot32);
    k_conv3x3<<<cdiv_i(tot32,256),256,0,stream>>>(buf_b, rb2_w2, rb2_b2, buf_a,  nullptr, buf_a, 32, 32, 0, tot32);
    k_conv3x3<<<cdiv_i(tot1,256),256,0,stream>>>(buf_a, tail_w, tail_b, duv, nullptr, xp, 32, 1, 0, tot1);

    k_duvw<<<cdiv_i(NSM,256),256,0,stream>>>(du, v_in, xp, beta_p, duvw, NSM);
    k_conv3x3<<<cdiv_i(tot1,256),256,0,stream>>>(duvw, conv2_w, nullptr, nullptr, nullptr, duvww, 1, 1, 1, tot1);
    k_rr<<<cdiv_i(NSM,256),256,0,stream>>>(duvww, r_in, x, xx_in, wa, uu_in, theta_p, ls_p, bn_g, bn_b, rr, bn1a, NSM);
    k_conv3x3<<<cdiv_i(tot64,256),256,0,stream>>>(bn1a, convG1_w, nullptr, nullptr, nullptr, rr3, 1, 64, 1, tot64);

    // attention
    k_b123<<<cdiv_i(BB*48*IMG,256),256,0,stream>>>(rr3, g_w, g_b, th_w, th_b, ph_w, ph_b, b1p, b2p, b3p, BB*48*IMG);
    {
        dim3 gs(BB * 5, 3);
        k_scores<<<gs, 128, 0, stream>>>(b1p, b3p, scores);
    }
    k_softmax<<<BB * NPATCH, 256, 0, stream>>>(scores);
    hipMemsetAsync(agg, 0, (size_t)BB * NPATCH * 784 * sizeof(float), stream);
    {
        dim3 ga(BB, 3, 6);
        k_agg<<<ga, 256, 0, stream>>>(scores, b2p, agg);
    }
    k_fold<<<cdiv_i(BB*CATT*IMG,256),256,0,stream>>>(agg, y_att, BB*CATT*IMG);
    k_conv1x1<<<cdiv_i(BB*64*IMG,256),256,0,stream>>>(y_att, W_w, W_b, rr3, ybuf, 16, 64, BB*64*IMG);
    k_conv3x3<<<cdiv_i(tot1,256),256,0,stream>>>(ybuf, convG2_w, nullptr, rr, nullptr, rr_nl, 64, 1, 0, tot1);

    // ISTA soft-threshold stage
    k_conv3x3<<<cdiv_i(tot32,256),256,0,stream>>>(rr_nl, convD_w,  nullptr, nullptr, nullptr, buf_a, 1, 32, 0, tot32);
    k_conv3x3<<<cdiv_i(tot32,256),256,0,stream>>>(buf_a, conv1f_w, nullptr, nullptr, nullptr, buf_b, 32, 32, 1, tot32);
    k_conv3x3<<<cdiv_i(tot32,256),256,0,stream>>>(buf_b, conv2f_w, nullptr, nullptr, thr_p,   buf_a, 32, 32, 2, tot32);
    k_conv3x3<<<cdiv_i(tot32,256),256,0,stream>>>(buf_a, conv1b_w, nullptr, nullptr, nullptr, buf_b, 32, 32, 1, tot32);
    k_conv3x3<<<cdiv_i(tot32,256),256,0,stream>>>(buf_b, conv2b_w, nullptr, nullptr, nullptr, buf_a, 32, 32, 0, tot32);
    k_conv3x3<<<cdiv_i(tot1,256),256,0,stream>>>(buf_a, convG_w, nullptr, rr_nl, nullptr, (float*)d_out, 32, 1, 0, tot1);
}

// Round 4
// 2854.768 us; speedup vs baseline: 1.2025x; 1.1875x over previous
//
#include <hip/hip_runtime.h>

#define BB 64
#define PP 33
#define IMG 1089        // 33*33
#define MM 272
#define NP1 9
#define NPATCH 81
#define KK 7
#define KK2 49
#define CATT 16
#define PADW 39
#define PIMG 1521       // 39*39

static __host__ __device__ inline int cdiv_i(int a, int b) { return (a + b - 1) / b; }

// ---------------- generic 32x32 tiled transpose: in[R][C] -> out[C][R]
__global__ __launch_bounds__(256) void k_tr(
    const float* __restrict__ in, float* __restrict__ out, int R, int C)
{
    __shared__ float t[32][33];
    int c0 = blockIdx.x * 32, r0 = blockIdx.y * 32;
    int tx = threadIdx.x, ty = threadIdx.y;
    for (int i = ty; i < 32; i += 8) {
        int r = r0 + i, c = c0 + tx;
        if (r < R && c < C) t[i][tx] = in[(size_t)r * C + c];
    }
    __syncthreads();
    for (int i = ty; i < 32; i += 8) {
        int c = c0 + i, r = r0 + tx;
        if (c < C && r < R) out[(size_t)c * R + r] = t[tx][i];
    }
}

// ---------------- Phi forward (coalesced via PhiWT[j][m]): Phi_x[b,m], aubru
__global__ __launch_bounds__(320) void k_phi(
    const float* __restrict__ x, const float* __restrict__ PhiWT,
    const float* __restrict__ Phix_in, const float* __restrict__ ru,
    const float* __restrict__ mu_p,
    float* __restrict__ Phi_x, float* __restrict__ aubru)
{
    int b = blockIdx.x, tid = threadIdx.x;
    __shared__ float xs[IMG];
    for (int i = tid; i < IMG; i += 320) xs[i] = x[b * IMG + i];
    __syncthreads();
    if (tid >= MM) return;
    float mu = mu_p[0];
    const float* w = PhiWT + tid;
    float acc = 0.f;
    #pragma unroll 4
    for (int j = 0; j < IMG; ++j) acc += xs[j] * w[(size_t)j * MM];
    Phi_x[b * MM + tid] = acc;
    aubru[b * MM + tid] = mu * (acc - Phix_in[b * MM + tid]) - ru[b * MM + tid];
}

// ---------------- du, duv, wa (coalesced via PhiTWT[m][c])
__global__ __launch_bounds__(256) void k_duv(
    const float* __restrict__ x, const float* __restrict__ v_in,
    const float* __restrict__ PhiTb, const float* __restrict__ PhiTWT,
    const float* __restrict__ Phi_x, const float* __restrict__ aubru,
    const float* __restrict__ conv1_w,
    const float* __restrict__ beta_p, const float* __restrict__ ls2_p,
    float* __restrict__ du, float* __restrict__ duv, float* __restrict__ wa)
{
    int b = blockIdx.y, tid = threadIdx.x;
    __shared__ float xs[IMG];
    __shared__ float ps[MM], as_[MM];
    for (int i = tid; i < IMG; i += 256) xs[i] = x[b * IMG + i];
    for (int i = tid; i < MM; i += 256) { ps[i] = Phi_x[b * MM + i]; as_[i] = aubru[b * MM + i]; }
    __syncthreads();
    int c = blockIdx.x * 256 + tid;
    if (c >= IMG) return;
    float binv = 1.f / beta_p[0];
    float ls2 = ls2_p[0];
    int y = c / PP, xq = c % PP;
    float dacc = 0.f;
    #pragma unroll
    for (int dy = 0; dy < 3; ++dy) {
        int yy = y + dy - 1;
        if ((unsigned)yy >= (unsigned)PP) continue;
        #pragma unroll
        for (int dx = 0; dx < 3; ++dx) {
            int xc = xq + dx - 1;
            if ((unsigned)xc >= (unsigned)PP) continue;
            dacc += xs[yy * PP + xc] * conv1_w[dy * 3 + dx];
        }
    }
    dacc = fmaxf(dacc, 0.f);
    const float* pt = PhiTWT + c;
    float s1 = 0.f, s2 = 0.f;
    #pragma unroll 4
    for (int m = 0; m < MM; ++m) {
        float t = pt[(size_t)m * IMG];
        s1 += ps[m] * t; s2 += as_[m] * t;
    }
    int o = b * IMG + c;
    du[o] = dacc;
    duv[o] = dacc - v_in[o] * binv + ls2 * (PhiTb[o] - s1);
    wa[o] = s2;
}

// ---------------- generic 3x3 same-pad conv, 4-pixel x-strip per thread
__global__ __launch_bounds__(256) void k_conv3x3(
    const float* __restrict__ in, const float* __restrict__ w,
    const float* __restrict__ bias, const float* __restrict__ add,
    const float* __restrict__ thr_p, float* __restrict__ out,
    int Cin, int Cout, int epil, int total)
{
    int gid = blockIdx.x * 256 + threadIdx.x;
    if (gid >= total) return;
    int s = gid % 9; int t1 = gid / 9;
    int y = t1 % PP; int t2 = t1 / PP;
    int co = t2 % Cout; int b = t2 / Cout;
    int x0 = s * 4;
    float a0 = 0.f, a1 = 0.f, a2 = 0.f, a3 = 0.f;
    const float* wb = w + (size_t)co * Cin * 9;
    const float* ib = in + (size_t)b * Cin * IMG;
    for (int ci = 0; ci < Cin; ++ci) {
        const float* img = ib + ci * IMG;
        const float* wk = wb + ci * 9;
        #pragma unroll
        for (int dy = 0; dy < 3; ++dy) {
            int yy = y + dy - 1;
            if ((unsigned)yy >= (unsigned)PP) continue;
            const float* row = img + yy * PP;
            float wA = wk[dy * 3 + 0], wB = wk[dy * 3 + 1], wC = wk[dy * 3 + 2];
            float r0 = (x0 - 1 >= 0) ? row[x0 - 1] : 0.f;
            float r1 = row[x0];
            float r2 = (x0 + 1 < PP) ? row[x0 + 1] : 0.f;
            float r3 = (x0 + 2 < PP) ? row[x0 + 2] : 0.f;
            float r4 = (x0 + 3 < PP) ? row[x0 + 3] : 0.f;
            float r5 = (x0 + 4 < PP) ? row[x0 + 4] : 0.f;
            a0 += r0 * wA + r1 * wB + r2 * wC;
            a1 += r1 * wA + r2 * wB + r3 * wC;
            a2 += r2 * wA + r3 * wB + r4 * wC;
            a3 += r3 * wA + r4 * wB + r5 * wC;
        }
    }
    float bs = bias ? bias[co] : 0.f;
    float thr = (epil == 2) ? thr_p[0] : 0.f;
    float accs[4] = {a0, a1, a2, a3};
    int obase = (b * Cout + co) * IMG + y * PP;
    #pragma unroll
    for (int k = 0; k < 4; ++k) {
        int xk = x0 + k;
        if (xk >= PP) break;
        float vv = accs[k] + bs;
        if (add) vv += add[obase + xk];
        if (epil == 1) vv = fmaxf(vv, 0.f);
        else if (epil == 2) {
            float av = fabsf(vv) - thr;
            vv = (vv >= 0.f ? 1.f : -1.f) * fmaxf(av, 0.f);
        }
        out[obase + xk] = vv;
    }
}

// ---------------- duvw = beta*du - v - beta*x_pred
__global__ __launch_bounds__(256) void k_duvw(
    const float* __restrict__ du, const float* __restrict__ v_in,
    const float* __restrict__ xp, const float* __restrict__ beta_p,
    float* __restrict__ duvw, int total)
{
    int g = blockIdx.x * 256 + threadIdx.x;
    if (g >= total) return;
    float beta = beta_p[0];
    duvw[g] = beta * du[g] - v_in[g] - beta * xp[g];
}

// ---------------- d, uu2, rr, bn1a
__global__ __launch_bounds__(256) void k_rr(
    const float* __restrict__ duvww, const float* __restrict__ r_in,
    const float* __restrict__ x_in, const float* __restrict__ xx_in,
    const float* __restrict__ wa, const float* __restrict__ uu_in,
    const float* __restrict__ theta_p, const float* __restrict__ ls_p,
    const float* __restrict__ bn_g, const float* __restrict__ bn_b,
    float* __restrict__ rr, float* __restrict__ bn1a, int total)
{
    int g = blockIdx.x * 256 + threadIdx.x;
    if (g >= total) return;
    float theta = theta_p[0], ls = ls_p[0];
    float d = duvww[g] - r_in[g] + theta * (x_in[g] - xx_in[g]) + wa[g];
    float uu2 = uu_in[g] - ls * d;
    float rrv = uu2 - r_in[g] / theta;
    rr[g] = rrv;
    bn1a[g] = bn_g[0] * rrv * 0.9999950000374997f + bn_b[0];
}

// ---------------- b1/b2/b3 = 1x1 conv (64->16) + bias into zero-padded 39x39
__global__ __launch_bounds__(256) void k_b123(
    const float* __restrict__ rr3,
    const float* __restrict__ g_w, const float* __restrict__ g_b,
    const float* __restrict__ th_w, const float* __restrict__ th_b,
    const float* __restrict__ ph_w, const float* __restrict__ ph_b,
    float* __restrict__ b1p, float* __restrict__ b2p, float* __restrict__ b3p, int total)
{
    int g = blockIdx.x * 256 + threadIdx.x;
    if (g >= total) return;
    int j = g % IMG; int t = g / IMG; int o = t % 48; int b = t / 48;
    int sel = o / 16, co = o % 16;
    const float* w = sel == 0 ? g_w : (sel == 1 ? th_w : ph_w);
    const float* bi = sel == 0 ? g_b : (sel == 1 ? th_b : ph_b);
    float* outp = sel == 0 ? b1p : (sel == 1 ? b2p : b3p);
    const float* wr = w + co * 64;
    const float* ip = rr3 + (size_t)b * 64 * IMG + j;
    float acc = bi[co];
    #pragma unroll 8
    for (int ci = 0; ci < 64; ++ci) acc += ip[(size_t)ci * IMG] * wr[ci];
    int y = j / PP, xq = j % PP;
    outp[((size_t)(b * CATT + co) * PADW + y + 3) * PADW + (xq + 3)] = acc;
}

// ---------------- scores: LDS-staged q (float4 broadcast), 2 pixels/thread, 28-p groups
// grid: (64*5, 3), block 128.  scores[b,p,pix] = <query p, key patch at pix>
__global__ __launch_bounds__(128) void k_scores(
    const float* __restrict__ b1p, const float* __restrict__ b3p,
    float* __restrict__ scores)
{
    __shared__ float qs[KK2][28];
    int b = blockIdx.x / 5, chunk = blockIdx.x % 5;
    int p0 = blockIdx.y * 28;
    int tid = threadIdx.x;

    int pixA = chunk * 128 + tid;            // [0, 640)
    int validA = pixA < 545;
    int validB = pixA < 544;
    int pixB = validB ? pixA + 545 : pixA;   // clamp keeps loads in-bounds
    int yA = pixA < IMG ? pixA / PP : 0, xA = pixA < IMG ? pixA % PP : 0;
    int yB = pixB / PP, xB = pixB % PP;

    float accA[28], accB[28];
    #pragma unroll
    for (int i = 0; i < 28; ++i) { accA[i] = 0.f; accB[i] = 0.f; }

    for (int c = 0; c < CATT; ++c) {
        __syncthreads();
        for (int idx = tid; idx < KK2 * 28; idx += 128) {
            int k = idx / 28, pp = idx % 28;
            int p = p0 + pp;
            float v = 0.f;
            if (p < NPATCH) {
                int py = p / NP1, px = p % NP1;
                int row = 4 * py + k / KK, col = 4 * px + k % KK;
                v = b1p[((size_t)(b * CATT + c) * PADW + row) * PADW + col];
            }
            qs[k][pp] = v;
        }
        __syncthreads();
        const float* plane = b3p + (size_t)(b * CATT + c) * PIMG;
        #pragma unroll
        for (int ky = 0; ky < KK; ++ky) {
            const float* baseA = plane + (yA + ky) * PADW + xA;
            const float* baseB = plane + (yB + ky) * PADW + xB;
            float rA[KK], rB[KK];
            #pragma unroll
            for (int i = 0; i < KK; ++i) { rA[i] = baseA[i]; rB[i] = baseB[i]; }
            #pragma unroll
            for (int kx = 0; kx < KK; ++kx) {
                int k = ky * KK + kx;
                const float4* q4 = (const float4*)(&qs[k][0]);
                float a = rA[kx], bb = rB[kx];
                #pragma unroll
                for (int pq = 0; pq < 7; ++pq) {
                    float4 q = q4[pq];
                    accA[pq * 4 + 0] += q.x * a;  accB[pq * 4 + 0] += q.x * bb;
                    accA[pq * 4 + 1] += q.y * a;  accB[pq * 4 + 1] += q.y * bb;
                    accA[pq * 4 + 2] += q.z * a;  accB[pq * 4 + 2] += q.z * bb;
                    accA[pq * 4 + 3] += q.w * a;  accB[pq * 4 + 3] += q.w * bb;
                }
            }
        }
    }
    #pragma unroll
    for (int pp = 0; pp < 28; ++pp) {
        int p = p0 + pp;
        if (p >= NPATCH) break;
        size_t rowb = (size_t)(b * NPATCH + p) * IMG;
        if (validA) scores[rowb + pixA] = accA[pp];
        if (validB) scores[rowb + pixA + 545] = accB[pp];
    }
}

// ---------------- row softmax over 1089 (in-place), scale 10
__global__ __launch_bounds__(256) void k_softmax(float* __restrict__ sc)
{
    int row = blockIdx.x;
    float* p = sc + (size_t)row * IMG;
    __shared__ float red[256];
    int tid = threadIdx.x;
    float v[5];
    float m = -1e30f;
    #pragma unroll
    for (int i = 0; i < 5; ++i) {
        int idx = tid + i * 256;
        v[i] = (idx < IMG) ? p[idx] : -1e30f;
        m = fmaxf(m, v[i]);
    }
    red[tid] = m; __syncthreads();
    for (int s = 128; s > 0; s >>= 1) { if (tid < s) red[tid] = fmaxf(red[tid], red[tid + s]); __syncthreads(); }
    m = red[0]; __syncthreads();
    float sum = 0.f;
    #pragma unroll
    for (int i = 0; i < 5; ++i) {
        int idx = tid + i * 256;
        float e = (idx < IMG) ? __expf(10.f * (v[i] - m)) : 0.f;
        v[i] = e; sum += e;
    }
    red[tid] = sum; __syncthreads();
    for (int s = 128; s > 0; s >>= 1) { if (tid < s) red[tid] += red[tid + s]; __syncthreads(); }
    float inv = 1.f / red[0];
    #pragma unroll
    for (int i = 0; i < 5; ++i) {
        int idx = tid + i * 256;
        if (idx < IMG) p[idx] = v[i] * inv;
    }
}

// ---------------- agg v3: atomic-free. thread = (c_local, k) lane, 27 p-accumulators,
// full 33x33 pixel loop; attn reads are wave-uniform (scalarizable, dwordx4 after x-unroll).
// grid (BB, 4 c-groups, 3 p-groups), block 256 = 4c x 64 (49 active lanes).
__global__ __launch_bounds__(256) void k_agg(
    const float* __restrict__ attn, const float* __restrict__ b2p,
    float* __restrict__ agg)
{
    int b = blockIdx.x;
    int c = blockIdx.y * 4 + (threadIdx.x >> 6);
    int k = threadIdx.x & 63;
    int p0 = blockIdx.z * 27;
    if (k >= KK2) return;
    int oy = k / KK, ox = k % KK;
    const float* vp = b2p + ((size_t)(b * CATT + c) * PADW + oy) * PADW + ox;
    const float* ap = attn + (size_t)(b * NPATCH + p0) * IMG;
    float acc[27];
    #pragma unroll
    for (int p = 0; p < 27; ++p) acc[p] = 0.f;
    for (int y = 0; y < PP; ++y) {
        const float* ar = ap + y * PP;
        const float* vr = vp + y * PADW;
        #pragma unroll 1
        for (int x = 0; x < 32; x += 4) {
            float v0 = vr[x], v1 = vr[x + 1], v2 = vr[x + 2], v3 = vr[x + 3];
            #pragma unroll
            for (int p = 0; p < 27; ++p) {
                const float* a = ar + (size_t)p * IMG + x;
                acc[p] += a[0] * v0 + a[1] * v1 + a[2] * v2 + a[3] * v3;
            }
        }
        {   // tail x = 32
            float v0 = vr[32];
            #pragma unroll
            for (int p = 0; p < 27; ++p) acc[p] += ar[(size_t)p * IMG + 32] * v0;
        }
    }
    #pragma unroll
    for (int p = 0; p < 27; ++p)
        agg[(size_t)((b * NPATCH + p0 + p) * CATT + c) * KK2 + k] = acc[p];
}

// ---------------- fold + count normalize + crop -> y_att[b,c,33,33]
__global__ __launch_bounds__(256) void k_fold(
    const float* __restrict__ agg, float* __restrict__ y_att, int total)
{
    int g = blockIdx.x * 256 + threadIdx.x;
    if (g >= total) return;
    int j = g % IMG; int t = g / IMG; int c = t % CATT; int b = t / CATT;
    int y = j / PP, x = j % PP;
    int yp = y + 3, xp = x + 3;
    int pylo = (yp - 3) >> 2; int pyhi = min(8, yp >> 2);
    int pxlo = (xp - 3) >> 2; int pxhi = min(8, xp >> 2);
    float sum = 0.f;
    int cnt = (pyhi - pylo + 1) * (pxhi - pxlo + 1);
    for (int py = pylo; py <= pyhi; ++py) {
        int ky = yp - 4 * py;
        for (int px = pxlo; px <= pxhi; ++px) {
            int kx = xp - 4 * px;
            sum += agg[(size_t)((b * NPATCH + py * NP1 + px) * CATT + c) * KK2 + ky * KK + kx];
        }
    }
    y_att[(size_t)(b * CATT + c) * IMG + j] = sum / (float)cnt;
}

// ---------------- 1x1 conv generic (W: 16->64, +bias, +rr3 residual)
__global__ __launch_bounds__(256) void k_conv1x1(
    const float* __restrict__ in, const float* __restrict__ w,
    const float* __restrict__ bias, const float* __restrict__ add,
    float* __restrict__ out, int Cin, int Cout, int total)
{
    int g = blockIdx.x * 256 + threadIdx.x;
    if (g >= total) return;
    int j = g % IMG; int t = g / IMG; int co = t % Cout; int b = t / Cout;
    const float* ip = in + (size_t)b * Cin * IMG + j;
    const float* wr = w + co * Cin;
    float acc = bias ? bias[co] : 0.f;
    #pragma unroll 4
    for (int ci = 0; ci < Cin; ++ci) acc += ip[(size_t)ci * IMG] * wr[ci];
    if (add) acc += add[g];
    out[g] = acc;
}

extern "C" void kernel_launch(void* const* d_in, const int* in_sizes, int n_in,
                              void* d_out, int out_size, void* d_ws, size_t ws_size,
                              hipStream_t stream)
{
    (void)in_sizes; (void)n_in; (void)out_size; (void)ws_size;
    const float* x      = (const float*)d_in[0];
    const float* PhiTb  = (const float*)d_in[1];
    const float* v_in   = (const float*)d_in[2];
    const float* r_in   = (const float*)d_in[3];
    const float* ru     = (const float*)d_in[4];
    const float* xx_in  = (const float*)d_in[5];
    const float* uu_in  = (const float*)d_in[6];
    const float* Phix   = (const float*)d_in[7];
    const float* PhiW   = (const float*)d_in[8];
    const float* PhiTW  = (const float*)d_in[9];
    const float* ls_p   = (const float*)d_in[10];
    const float* ls2_p  = (const float*)d_in[11];
    const float* thr_p  = (const float*)d_in[12];
    const float* beta_p = (const float*)d_in[13];
    const float* mu_p   = (const float*)d_in[14];
    const float* theta_p= (const float*)d_in[15];
    const float* conv1_w  = (const float*)d_in[16];
    const float* conv2_w  = (const float*)d_in[17];
    const float* convG1_w = (const float*)d_in[18];
    const float* convD_w  = (const float*)d_in[19];
    const float* conv1f_w = (const float*)d_in[20];
    const float* conv2f_w = (const float*)d_in[21];
    const float* conv1b_w = (const float*)d_in[22];
    const float* conv2b_w = (const float*)d_in[23];
    const float* convG_w  = (const float*)d_in[24];
    const float* convG2_w = (const float*)d_in[25];
    const float* head_w = (const float*)d_in[26];
    const float* head_b = (const float*)d_in[27];
    const float* tail_w = (const float*)d_in[28];
    const float* tail_b = (const float*)d_in[29];
    const float* rb1_w1 = (const float*)d_in[30];
    const float* rb1_b1 = (const float*)d_in[31];
    const float* rb1_w2 = (const float*)d_in[32];
    const float* rb1_b2 = (const float*)d_in[33];
    const float* rb2_w1 = (const float*)d_in[34];
    const float* rb2_b1 = (const float*)d_in[35];
    const float* rb2_w2 = (const float*)d_in[36];
    const float* rb2_b2 = (const float*)d_in[37];
    const float* g_w  = (const float*)d_in[38];
    const float* g_b  = (const float*)d_in[39];
    const float* th_w = (const float*)d_in[40];
    const float* th_b = (const float*)d_in[41];
    const float* ph_w = (const float*)d_in[42];
    const float* ph_b = (const float*)d_in[43];
    const float* W_w  = (const float*)d_in[44];
    const float* W_b  = (const float*)d_in[45];
    const float* bn_g = (const float*)d_in[46];
    const float* bn_b = (const float*)d_in[47];

    const int NSM = BB * IMG;            // 69696
    float* ws = (float*)d_ws;
    float* du    = ws;
    float* Phi_x = du + NSM;
    float* aubru = Phi_x + BB * MM;
    float* duv   = aubru + BB * MM;
    float* wa    = duv + NSM;
    float* duvw  = wa + NSM;
    float* rr    = duvw + NSM;
    float* bn1a  = rr + NSM;
    float* rr_nl = bn1a + NSM;
    float* xp    = rr_nl + NSM;
    float* duvww = xp + NSM;
    float* rr3   = duvww + NSM;                        // B*64*IMG
    float* R7    = rr3 + (size_t)BB * 64 * IMG;        // buf_a|buf_b; reused as agg
    float* buf_a = R7;
    float* buf_b = R7 + (size_t)BB * 32 * IMG;
    float* agg   = R7;                                  // 64*81*784 = 4.06M floats < 4.46M
    float* b1p   = R7 + (size_t)2 * BB * 32 * IMG;     // padded 39x39 x16ch
    float* b2p   = b1p + (size_t)BB * CATT * PIMG;
    float* b3p   = b2p + (size_t)BB * CATT * PIMG;
    float* y_att = b1p;                                 // reuse (b1p dead after k_scores)
    float* scores= b3p + (size_t)BB * CATT * PIMG;      // B*81*IMG
    float* ybuf  = scores;                              // reuse (attn dead after k_agg)
    float* PhiWT = scores + (size_t)BB * NPATCH * IMG;  // [1089][272]
    float* PhiTWT= PhiWT + (size_t)MM * IMG;            // [272][1089]

    const int tot32 = BB * 32 * PP * 9;
    const int tot64 = BB * 64 * PP * 9;
    const int tot1  = BB * 1  * PP * 9;

    // zero padded b1p/b2p/b3p (borders must be 0; ws re-poisoned each call)
    hipMemsetAsync(b1p, 0, (size_t)3 * BB * CATT * PIMG * sizeof(float), stream);

    // transpose measurement operators (once per call; capture-safe)
    {
        dim3 blk(32, 8);
        dim3 g1(cdiv_i(IMG, 32), cdiv_i(MM, 32));   // PhiW[272][1089] -> PhiWT[1089][272]
        k_tr<<<g1, blk, 0, stream>>>(PhiW, PhiWT, MM, IMG);
        dim3 g2(cdiv_i(MM, 32), cdiv_i(IMG, 32));   // PhiTW[1089][272] -> PhiTWT[272][1089]
        k_tr<<<g2, blk, 0, stream>>>(PhiTW, PhiTWT, IMG, MM);
    }

    k_phi<<<BB, 320, 0, stream>>>(x, PhiWT, Phix, ru, mu_p, Phi_x, aubru);
    {
        dim3 gd(cdiv_i(IMG, 256), BB);
        k_duv<<<gd, 256, 0, stream>>>(x, v_in, PhiTb, PhiTWT, Phi_x, aubru, conv1_w, beta_p, ls2_p, du, duv, wa);
    }

    // denoiser: head + 2 resblocks + tail
    k_conv3x3<<<cdiv_i(tot32,256),256,0,stream>>>(duv,  head_w, head_b, nullptr, nullptr, buf_a, 1, 32, 0, tot32);
    k_conv3x3<<<cdiv_i(tot32,256),256,0,stream>>>(buf_a, rb1_w1, rb1_b1, nullptr, nullptr, buf_b, 32, 32, 1, tot32);
    k_conv3x3<<<cdiv_i(tot32,256),256,0,stream>>>(buf_b, rb1_w2, rb1_b2, buf_a,  nullptr, buf_a, 32, 32, 0, tot32);
    k_conv3x3<<<cdiv_i(tot32,256),256,0,stream>>>(buf_a, rb2_w1, rb2_b1, nullptr, nullptr, buf_b, 32, 32, 1, tot32);
    k_conv3x3<<<cdiv_i(tot32,256),256,0,stream>>>(buf_b, rb2_w2, rb2_b2, buf_a,  nullptr, buf_a, 32, 32, 0, tot32);
    k_conv3x3<<<cdiv_i(tot1,256),256,0,stream>>>(buf_a, tail_w, tail_b, duv, nullptr, xp, 32, 1, 0, tot1);

    k_duvw<<<cdiv_i(NSM,256),256,0,stream>>>(du, v_in, xp, beta_p, duvw, NSM);
    k_conv3x3<<<cdiv_i(tot1,256),256,0,stream>>>(duvw, conv2_w, nullptr, nullptr, nullptr, duvww, 1, 1, 1, tot1);
    k_rr<<<cdiv_i(NSM,256),256,0,stream>>>(duvww, r_in, x, xx_in, wa, uu_in, theta_p, ls_p, bn_g, bn_b, rr, bn1a, NSM);
    k_conv3x3<<<cdiv_i(tot64,256),256,0,stream>>>(bn1a, convG1_w, nullptr, nullptr, nullptr, rr3, 1, 64, 1, tot64);

    // attention
    k_b123<<<cdiv_i(BB*48*IMG,256),256,0,stream>>>(rr3, g_w, g_b, th_w, th_b, ph_w, ph_b, b1p, b2p, b3p, BB*48*IMG);
    {
        dim3 gs(BB * 5, 3);
        k_scores<<<gs, 128, 0, stream>>>(b1p, b3p, scores);
    }
    k_softmax<<<BB * NPATCH, 256, 0, stream>>>(scores);
    {
        dim3 ga(BB, 4, 3);
        k_agg<<<ga, 256, 0, stream>>>(scores, b2p, agg);
    }
    k_fold<<<cdiv_i(BB*CATT*IMG,256),256,0,stream>>>(agg, y_att, BB*CATT*IMG);
    k_conv1x1<<<cdiv_i(BB*64*IMG,256),256,0,stream>>>(y_att, W_w, W_b, rr3, ybuf, 16, 64, BB*64*IMG);
    k_conv3x3<<<cdiv_i(tot1,256),256,0,stream>>>(ybuf, convG2_w, nullptr, rr, nullptr, rr_nl, 64, 1, 0, tot1);

    // ISTA soft-threshold stage
    k_conv3x3<<<cdiv_i(tot32,256),256,0,stream>>>(rr_nl, convD_w,  nullptr, nullptr, nullptr, buf_a, 1, 32, 0, tot32);
    k_conv3x3<<<cdiv_i(tot32,256),256,0,stream>>>(buf_a, conv1f_w, nullptr, nullptr, nullptr, buf_b, 32, 32, 1, tot32);
    k_conv3x3<<<cdiv_i(tot32,256),256,0,stream>>>(buf_b, conv2f_w, nullptr, nullptr, thr_p,   buf_a, 32, 32, 2, tot32);
    k_conv3x3<<<cdiv_i(tot32,256),256,0,stream>>>(buf_a, conv1b_w, nullptr, nullptr, nullptr, buf_b, 32, 32, 1, tot32);
    k_conv3x3<<<cdiv_i(tot32,256),256,0,stream>>>(buf_b, conv2b_w, nullptr, nullptr, nullptr, buf_a, 32, 32, 0, tot32);
    k_conv3x3<<<cdiv_i(tot1,256),256,0,stream>>>(buf_a, convG_w, nullptr, rr_nl, nullptr, (float*)d_out, 32, 1, 0, tot1);
}